// Round 13
// baseline (350.037 us; speedup 1.0000x reference)
//
#include <hip/hip_runtime.h>

#define DIM 64
#define RNG 8        // node ranges per graph (LDS-owned)
#define CHK 16       // edge chunks per graph (384 blocks ~1.5/CU)
#define LDSH 14336   // LDS histogram/cursor capacity (ints); ceil(110000/8)=13750 fits
#define EPT 64       // final: edges per wave (4 tiles of 16, pipelined)

typedef __attribute__((ext_vector_type(4))) short s16x4;
typedef __attribute__((ext_vector_type(4))) float f32x4v;

__device__ __forceinline__ float bf2f(unsigned short u) {
    union { unsigned int i; float f; } v; v.i = ((unsigned int)u) << 16; return v.f;
}
__device__ __forceinline__ unsigned short f2bf(float f) {
    union { float f; unsigned int i; } v; v.f = f;
    unsigned int r = v.i + 0x7fff + ((v.i >> 16) & 1);   // RNE (no NaN inputs here)
    return (unsigned short)(r >> 16);
}
__device__ __forceinline__ float4 u2f4(ushort4 u) {
    float4 f; f.x = bf2f(u.x); f.y = bf2f(u.y); f.z = bf2f(u.z); f.w = bf2f(u.w);
    return f;
}
__device__ __forceinline__ ushort4 f2u4(float4 f) {
    ushort4 u; u.x = f2bf(f.x); u.y = f2bf(f.y); u.z = f2bf(f.z); u.w = f2bf(f.w);
    return u;
}
__device__ __forceinline__ float4 fma4(float4 a, float s, float4 c) {
    c.x = fmaf(a.x, s, c.x); c.y = fmaf(a.y, s, c.y);
    c.z = fmaf(a.z, s, c.z); c.w = fmaf(a.w, s, c.w);
    return c;
}
__device__ __forceinline__ float4 add4(float4 a, float4 b) {
    float4 r; r.x = a.x + b.x; r.y = a.y + b.y; r.z = a.z + b.z; r.w = a.w + b.w;
    return r;
}

// ---- deg (LDS histograms, ZERO global atomics) + emb fp32->bf16 convert
//      + one ride-along block building the bf16 MFMA B-fragment table ----
__global__ __launch_bounds__(1024) void deg_cvt_kernel(
        const int* __restrict__ up, const int* __restrict__ ut,
        const int* __restrict__ ug, int* __restrict__ hist,
        const float4* __restrict__ e0, const float4* __restrict__ e1,
        const float4* __restrict__ e2, ushort4* __restrict__ embh,
        const float* __restrict__ W_s, const float* __restrict__ W_d,
        s16x4* __restrict__ wfrag,
        int NP, int NT, int NG, int NTOT, int E) {
    __shared__ int lh[LDSH];
    int b = blockIdx.x;
    const int HB = 3 * RNG * CHK;
    if (b < HB) {
        int c  = b & (CHK - 1);
        int gr = b >> 4;             // CHK==16
        int g  = gr >> 3;            // RNG==8
        int r  = gr & (RNG - 1);
        const int* edge = (g == 0) ? up : (g == 1) ? ut : ug;
        int nb = (g == 0) ? 0 : (g == 1) ? NP : NP + NT;
        int Ng = (g == 0) ? NP : (g == 1) ? NT : NG;
        int Q  = (Ng + RNG - 1) / RNG;
        int lo = r * Q;
        int hi = lo + Q; if (hi > Ng) hi = Ng;
        int nloc = hi - lo;
        for (int t = threadIdx.x; t < nloc; t += 1024) lh[t] = 0;
        __syncthreads();
        int CE = (E + CHK - 1) / CHK;
        int jb = c * CE, je = jb + CE; if (je > E) je = E;
        for (int j = jb + threadIdx.x; j < je; j += 1024) {
            int t = edge[E + j];                         // dst (local id)
            if (t >= lo && t < hi) atomicAdd(&lh[t - lo], 1);
        }
        __syncthreads();
        for (int t = threadIdx.x; t < nloc; t += 1024)
            hist[(size_t)c * NTOT + nb + lo + t] = lh[t];
        return;
    }
    int convBlocks = (NTOT * 16 + 1023) / 1024;
    if (b >= HB + convBlocks) {
        // ---- build wfrag (512 entries of s16x4) ----
        int i = threadIdx.x;
        if (i < 512) {
            int m = i >> 8;              // matrix (0=src,1=dst)
            int t = (i >> 6) & 3;        // tile
            int l = i & 63;              // lane
            int q = l >> 4, cc = l & 15;
            const float* Wm = m ? W_d : W_s;
            s16x4 v;
#pragma unroll
            for (int j = 0; j < 4; ++j)
                v[j] = (short)f2bf(Wm[(4 * q + j) * 64 + 4 * cc + t]);
            wfrag[i] = v;
        }
        return;
    }
    // ---- emb conversion blocks ----
    int i2 = (b - HB) * 1024 + threadIdx.x;
    int np16 = NP * 16, nt16 = NT * 16, ng16 = NG * 16;
    if (i2 >= np16 + nt16 + ng16) return;
    const float4* s; int j;
    if (i2 < np16)              { s = e0; j = i2; }
    else if (i2 < np16 + nt16)  { s = e1; j = i2 - np16; }
    else                        { s = e2; j = i2 - np16 - nt16; }
    embh[i2] = f2u4(s[j]);
}

// ---- chunk-prefix + total degree ----
__global__ void sumdeg_kernel(const int* __restrict__ hist, int* __restrict__ csum,
                              int* __restrict__ deg, int n) {
    int i = blockIdx.x * 256 + threadIdx.x;
    if (i >= n) return;
    int run = 0;
#pragma unroll
    for (int c = 0; c < CHK; ++c) {
        csum[(size_t)c * n + i] = run;          // exclusive chunk prefix
        run += hist[(size_t)c * n + i];
    }
    deg[i] = run;
}

// ---- parallel scan, stage 1: per-block (256-elem) sums over deg ----
__global__ void block_sums(const int* __restrict__ deg, int* __restrict__ bsum,
                           int n) {
    int i = blockIdx.x * 256 + threadIdx.x;
    int v = (i < n) ? deg[i] : 0;
#pragma unroll
    for (int s = 1; s < 64; s <<= 1) v += __shfl_xor(v, s, 64);
    __shared__ int ws[4];
    if ((threadIdx.x & 63) == 0) ws[threadIdx.x >> 6] = v;
    __syncthreads();
    if (threadIdx.x == 0) bsum[blockIdx.x] = ws[0] + ws[1] + ws[2] + ws[3];
}

// ---- stage 2: exclusive scan of block sums (single block, nb <= 1024) ----
__global__ void scan_bsums(int* __restrict__ bsum, int nb) {
    int lane = threadIdx.x & 63, wid = threadIdx.x >> 6;
    int v = (threadIdx.x < nb) ? bsum[threadIdx.x] : 0;
    int x = v;
#pragma unroll
    for (int s = 1; s < 64; s <<= 1) {
        int y = __shfl_up(x, s, 64);
        if (lane >= s) x += y;
    }
    __shared__ int ws[16];
    if (lane == 63) ws[wid] = x;
    __syncthreads();
    int pre = 0;
    for (int w2 = 0; w2 < wid; ++w2) pre += ws[w2];
    if (threadIdx.x < nb) bsum[threadIdx.x] = pre + x - v;   // exclusive
}

// ---- stage 3: global exclusive offsets + dinv ----
__global__ void scatter_offs(const int* __restrict__ deg, const int* __restrict__ bpre,
                             int* __restrict__ offs, float* __restrict__ dinv,
                             int n, int total) {
    int i = blockIdx.x * 256 + threadIdx.x;
    int lane = threadIdx.x & 63, wid = threadIdx.x >> 6;
    int v = (i < n) ? deg[i] : 0;
    int x = v;
#pragma unroll
    for (int s = 1; s < 64; s <<= 1) {
        int y = __shfl_up(x, s, 64);
        if (lane >= s) x += y;
    }
    __shared__ int ws[4];
    if (lane == 63) ws[wid] = x;
    __syncthreads();
    int pre = bpre[blockIdx.x];
    for (int w2 = 0; w2 < wid; ++w2) pre += ws[w2];
    if (i < n) {
        int e = pre + x - v;
        offs[i] = e;
        dinv[i] = (v > 0) ? rsqrtf((float)v) : 0.0f;
    }
    if (i == 0) offs[n] = total;
}

// ---- permute into dst-sorted CSR order (ZERO global atomics) ----
// XCD-ALIGNED DECODE: b = c*24 + gr; 24%8==0 so b%8 == gr%8 -- all CHK chunks
// of one (g,r) land on the SAME XCD; each 64B ei line written back once, full.
__global__ __launch_bounds__(1024) void permute3_kernel(
        const int* __restrict__ up, const int* __restrict__ ut,
        const int* __restrict__ ug, const int* __restrict__ offs,
        const int* __restrict__ csum, int* __restrict__ ei,
        int NP, int NT, int NG, int NTOT, int E) {
    __shared__ int lcur[LDSH];
    int b = blockIdx.x;
    int c  = b / 24;                 // chunk (0..CHK-1); 24 = 3*RNG (g,r) pairs
    int gr = b - c * 24;             // (g,r); b%8 == gr%8 -> XCD-aligned
    int g  = gr >> 3;
    int r  = gr & (RNG - 1);
    const int* edge = (g == 0) ? up : (g == 1) ? ut : ug;
    int nb = (g == 0) ? 0 : (g == 1) ? NP : NP + NT;
    int Ng = (g == 0) ? NP : (g == 1) ? NT : NG;
    int Q  = (Ng + RNG - 1) / RNG;
    int lo = r * Q;
    int hi = lo + Q; if (hi > Ng) hi = Ng;
    int nloc = hi - lo;
    for (int t = threadIdx.x; t < nloc; t += 1024)
        lcur[t] = offs[nb + lo + t] + csum[(size_t)c * NTOT + nb + lo + t];
    __syncthreads();
    int CE = (E + CHK - 1) / CHK;
    int jb = c * CE, je = jb + CE; if (je > E) je = E;
    for (int j = jb + threadIdx.x; j < je; j += 1024) {
        int t = edge[E + j];                             // dst (local id)
        if (t >= lo && t < hi) {
            int p = atomicAdd(&lcur[t - lo], 1);         // LDS atomic (on-CU)
            ei[p] = edge[j] + nb;                        // global src id
        }
    }
}

// ---- conv layer 1: x1[n] = dinv[n] * sum_in emb[s]*dinv[s]  (bf16 rows) ----
// r12: 8 loads in flight (2x MLP on the dominant random-row gathers),
// 4 accumulators at chain depth 2.
__global__ void conv_csr1(const int* __restrict__ offs, const int* __restrict__ ei,
                          const float* __restrict__ dinv,
                          const ushort4* __restrict__ xin, ushort4* __restrict__ xout, int N) {
    int gid = blockIdx.x * blockDim.x + threadIdx.x;
    int n = gid >> 4, l = gid & 15;
    if (n >= N) return;
    int beg = offs[n], end = offs[n + 1];
    float4 a0 = {0.f, 0.f, 0.f, 0.f}, a1 = a0, a2 = a0, a3 = a0;
    int k = beg;
    for (; k + 7 < end; k += 8) {
        int s0 = ei[k], s1 = ei[k + 1], s2 = ei[k + 2], s3 = ei[k + 3];
        int s4 = ei[k + 4], s5 = ei[k + 5], s6 = ei[k + 6], s7 = ei[k + 7];
        float w0 = dinv[s0], w1 = dinv[s1], w2 = dinv[s2], w3 = dinv[s3];
        float w4 = dinv[s4], w5 = dinv[s5], w6 = dinv[s6], w7 = dinv[s7];
        ushort4 u0 = xin[(size_t)s0 * 16 + l];
        ushort4 u1 = xin[(size_t)s1 * 16 + l];
        ushort4 u2 = xin[(size_t)s2 * 16 + l];
        ushort4 u3 = xin[(size_t)s3 * 16 + l];
        ushort4 u4 = xin[(size_t)s4 * 16 + l];
        ushort4 u5 = xin[(size_t)s5 * 16 + l];
        ushort4 u6 = xin[(size_t)s6 * 16 + l];
        ushort4 u7 = xin[(size_t)s7 * 16 + l];
        a0 = fma4(u2f4(u0), w0, a0);
        a1 = fma4(u2f4(u1), w1, a1);
        a2 = fma4(u2f4(u2), w2, a2);
        a3 = fma4(u2f4(u3), w3, a3);
        a0 = fma4(u2f4(u4), w4, a0);
        a1 = fma4(u2f4(u5), w5, a1);
        a2 = fma4(u2f4(u6), w6, a2);
        a3 = fma4(u2f4(u7), w7, a3);
    }
    for (; k + 3 < end; k += 4) {
        int s0 = ei[k], s1 = ei[k + 1], s2 = ei[k + 2], s3 = ei[k + 3];
        float w0 = dinv[s0], w1 = dinv[s1], w2 = dinv[s2], w3 = dinv[s3];
        ushort4 u0 = xin[(size_t)s0 * 16 + l];
        ushort4 u1 = xin[(size_t)s1 * 16 + l];
        ushort4 u2 = xin[(size_t)s2 * 16 + l];
        ushort4 u3 = xin[(size_t)s3 * 16 + l];
        a0 = fma4(u2f4(u0), w0, a0);
        a1 = fma4(u2f4(u1), w1, a1);
        a2 = fma4(u2f4(u2), w2, a2);
        a3 = fma4(u2f4(u3), w3, a3);
    }
    for (; k < end; ++k) {
        int s = ei[k];
        a0 = fma4(u2f4(xin[(size_t)s * 16 + l]), dinv[s], a0);
    }
    float4 acc = add4(add4(a0, a1), add4(a2, a3));
    float sc = dinv[n];
    float4 r; r.x = acc.x * sc; r.y = acc.y * sc; r.z = acc.z * sc; r.w = acc.w * sc;
    xout[(size_t)n * 16 + l] = f2u4(r);
}

// ---- conv layer 2 + epilogue (same 8-wide MLP) ----
__global__ void conv_csr2(const int* __restrict__ offs, const int* __restrict__ ei,
                          const float* __restrict__ dinv,
                          const ushort4* __restrict__ emb, const ushort4* __restrict__ x1,
                          ushort4* __restrict__ out, int N) {
    int gid = blockIdx.x * blockDim.x + threadIdx.x;
    int n = gid >> 4, l = gid & 15;
    if (n >= N) return;
    int beg = offs[n], end = offs[n + 1];
    float4 a0 = {0.f, 0.f, 0.f, 0.f}, a1 = a0, a2 = a0, a3 = a0;
    int k = beg;
    for (; k + 7 < end; k += 8) {
        int s0 = ei[k], s1 = ei[k + 1], s2 = ei[k + 2], s3 = ei[k + 3];
        int s4 = ei[k + 4], s5 = ei[k + 5], s6 = ei[k + 6], s7 = ei[k + 7];
        float w0 = dinv[s0], w1 = dinv[s1], w2 = dinv[s2], w3 = dinv[s3];
        float w4 = dinv[s4], w5 = dinv[s5], w6 = dinv[s6], w7 = dinv[s7];
        ushort4 u0 = x1[(size_t)s0 * 16 + l];
        ushort4 u1 = x1[(size_t)s1 * 16 + l];
        ushort4 u2 = x1[(size_t)s2 * 16 + l];
        ushort4 u3 = x1[(size_t)s3 * 16 + l];
        ushort4 u4 = x1[(size_t)s4 * 16 + l];
        ushort4 u5 = x1[(size_t)s5 * 16 + l];
        ushort4 u6 = x1[(size_t)s6 * 16 + l];
        ushort4 u7 = x1[(size_t)s7 * 16 + l];
        a0 = fma4(u2f4(u0), w0, a0);
        a1 = fma4(u2f4(u1), w1, a1);
        a2 = fma4(u2f4(u2), w2, a2);
        a3 = fma4(u2f4(u3), w3, a3);
        a0 = fma4(u2f4(u4), w4, a0);
        a1 = fma4(u2f4(u5), w5, a1);
        a2 = fma4(u2f4(u6), w6, a2);
        a3 = fma4(u2f4(u7), w7, a3);
    }
    for (; k + 3 < end; k += 4) {
        int s0 = ei[k], s1 = ei[k + 1], s2 = ei[k + 2], s3 = ei[k + 3];
        float w0 = dinv[s0], w1 = dinv[s1], w2 = dinv[s2], w3 = dinv[s3];
        ushort4 u0 = x1[(size_t)s0 * 16 + l];
        ushort4 u1 = x1[(size_t)s1 * 16 + l];
        ushort4 u2 = x1[(size_t)s2 * 16 + l];
        ushort4 u3 = x1[(size_t)s3 * 16 + l];
        a0 = fma4(u2f4(u0), w0, a0);
        a1 = fma4(u2f4(u1), w1, a1);
        a2 = fma4(u2f4(u2), w2, a2);
        a3 = fma4(u2f4(u3), w3, a3);
    }
    for (; k < end; ++k) {
        int s = ei[k];
        a0 = fma4(u2f4(x1[(size_t)s * 16 + l]), dinv[s], a0);
    }
    float4 acc = add4(add4(a0, a1), add4(a2, a3));
    float sc = dinv[n];
    size_t idx = (size_t)n * 16 + l;
    float4 em = u2f4(emb[idx]), x = u2f4(x1[idx]);
    const float third = 1.0f / 3.0f;
    float4 o;
    o.x = (em.x + x.x + acc.x * sc) * third;
    o.y = (em.y + x.y + acc.y * sc) * third;
    o.z = (em.z + x.z + acc.z * sc) * third;
    o.w = (em.w + x.w + acc.w * sc) * third;
    out[idx] = f2u4(o);
}

// ---- final v8: MFMA GEMM + 4-tile-per-wave pipeline ----
// v7 was single-shot: idx-load -> gathers -> epilogue, wave dies (7813 block
// launches each paying the full serial latency chain for 16 edges). v8: each
// wave processes 4 tiles; next tile's indices+features issue BEFORE this
// tile's epilogue (youngest in the vmcnt queue -> the epilogue's counted wait
// on the gathers does not drain them), so the idx-chain of tile t+1 hides
// under tile t's epilogue. B-frags/biases load once per wave (4x reuse).
__global__ __launch_bounds__(256) void final_kernel(
        const int* __restrict__ up_e, const int* __restrict__ ut_e,
        const int* __restrict__ utag_e,
        const float* __restrict__ src_feat, const float* __restrict__ dst_feat,
        const ushort4* __restrict__ O, const s16x4* __restrict__ wfrag,
        const float4* __restrict__ b_s4, const float4* __restrict__ b_d4,
        float* __restrict__ out, int E, int NP, int NT) {
    int tid = threadIdx.x;
    int wv = tid >> 6;             // wave in block
    int l  = tid & 63;             // lane
    int c  = l & 15;               // col = dim quad (dims 4c..4c+3)
    int q  = l >> 4;               // quad (0..3)
    int wbase = (blockIdx.x * 4 + wv) * EPT;
    if (wbase >= E) return;

    // B fragments + biases, once per wave
    s16x4 Bs[4], Bd[4];
#pragma unroll
    for (int t = 0; t < 4; ++t) {
        Bs[t] = wfrag[t * 64 + l];
        Bd[t] = wfrag[256 + t * 64 + l];
    }
    float4 bsv = b_s4[c], bdv = b_d4[c];
    const float third = 1.0f / 3.0f;

    // ---- tile-0 prefetch: A-row features + gather indices ----
    int ea = wbase + c; if (ea > E - 1) ea = E - 1;
    float4 fa = *(const float4*)(src_feat + (size_t)ea * 16 + q * 4);
    float4 ga = *(const float4*)(dst_feat + (size_t)ea * 16 + q * 4);
    int isp[4], idp[4], ist[4], idt[4], isg[4], idg[4];
#pragma unroll
    for (int r = 0; r < 4; ++r) {
        int e = wbase + q * 4 + r; if (e > E - 1) e = E - 1;
        isp[r] = up_e[e];             idp[r] = up_e[E + e];
        ist[r] = ut_e[e] + NP;        idt[r] = ut_e[E + e] + NP;
        isg[r] = utag_e[e] + NP + NT; idg[r] = utag_e[E + e] + NP + NT;
    }

    for (int t = 0; t < 4; ++t) {
        int tb = wbase + t * 16;
        if (tb >= E) break;

        // issue this tile's 24 row gathers (indices from previous prefetch)
        ushort4 as[4][3], bs[4][3];
#pragma unroll
        for (int r = 0; r < 4; ++r) {
            as[r][0] = O[(size_t)isp[r] * 16 + c];
            as[r][1] = O[(size_t)ist[r] * 16 + c];
            as[r][2] = O[(size_t)isg[r] * 16 + c];
            bs[r][0] = O[(size_t)idp[r] * 16 + c];
            bs[r][1] = O[(size_t)idt[r] * 16 + c];
            bs[r][2] = O[(size_t)idg[r] * 16 + c];
        }

        // convert this tile's A fragments (features prefetched last iter)
        s16x4 As, Ad;
        As[0] = (short)f2bf(fa.x); As[1] = (short)f2bf(fa.y);
        As[2] = (short)f2bf(fa.z); As[3] = (short)f2bf(fa.w);
        Ad[0] = (short)f2bf(ga.x); Ad[1] = (short)f2bf(ga.y);
        Ad[2] = (short)f2bf(ga.z); Ad[3] = (short)f2bf(ga.w);

        // prefetch next tile's features + indices (youngest VMEM ops)
        int nb2 = tb + 16;
        if (t < 3 && nb2 < E) {
            int ea2 = nb2 + c; if (ea2 > E - 1) ea2 = E - 1;
            fa = *(const float4*)(src_feat + (size_t)ea2 * 16 + q * 4);
            ga = *(const float4*)(dst_feat + (size_t)ea2 * 16 + q * 4);
#pragma unroll
            for (int r = 0; r < 4; ++r) {
                int e = nb2 + q * 4 + r; if (e > E - 1) e = E - 1;
                isp[r] = up_e[e];             idp[r] = up_e[E + e];
                ist[r] = ut_e[e] + NP;        idt[r] = ut_e[E + e] + NP;
                isg[r] = utag_e[e] + NP + NT; idg[r] = utag_e[E + e] + NP + NT;
            }
        }
        __builtin_amdgcn_sched_barrier(0);   // pin all loads above the MFMAs

        // 8 MFMAs (operands in regs; gathers + prefetch stay in flight)
        f32x4v Cs[4], Cd[4];
        f32x4v zz = {0.f, 0.f, 0.f, 0.f};
#pragma unroll
        for (int tt = 0; tt < 4; ++tt) {
            Cs[tt] = __builtin_amdgcn_mfma_f32_16x16x16bf16_1k(As, Bs[tt], zz, 0, 0, 0);
            Cd[tt] = __builtin_amdgcn_mfma_f32_16x16x16bf16_1k(Ad, Bd[tt], zz, 0, 0, 0);
        }

        // epilogue (counted vmcnt: waits gathers, not the younger prefetch)
#pragma unroll
        for (int r = 0; r < 4; ++r) {
            int er = tb + q * 4 + r;
            float4 fsv, fdv;
            fsv.x = Cs[0][r] + bsv.x; fsv.y = Cs[1][r] + bsv.y;
            fsv.z = Cs[2][r] + bsv.z; fsv.w = Cs[3][r] + bsv.w;
            fdv.x = Cd[0][r] + bdv.x; fdv.y = Cd[1][r] + bdv.y;
            fdv.z = Cd[2][r] + bdv.z; fdv.w = Cd[3][r] + bdv.w;
            float4 vp = u2f4(as[r][0]), vt = u2f4(as[r][1]), vg = u2f4(as[r][2]);
            float4 P, Q;
            P.x = (vp.x + vt.x + vg.x) * third + fsv.x;
            P.y = (vp.y + vt.y + vg.y) * third + fsv.y;
            P.z = (vp.z + vt.z + vg.z) * third + fsv.z;
            P.w = (vp.w + vt.w + vg.w) * third + fsv.w;
            vp = u2f4(bs[r][0]); vt = u2f4(bs[r][1]); vg = u2f4(bs[r][2]);
            Q.x = (vp.x + vt.x + vg.x) * third + fdv.x;
            Q.y = (vp.y + vt.y + vg.y) * third + fdv.y;
            Q.z = (vp.z + vt.z + vg.z) * third + fdv.z;
            Q.w = (vp.w + vt.w + vg.w) * third + fdv.w;
            float p = P.x * Q.x + P.y * Q.y + P.z * Q.z + P.w * Q.w;
            p += __shfl_xor(p, 8, 64);
            p += __shfl_xor(p, 4, 64);
            p += __shfl_xor(p, 2, 64);
            p += __shfl_xor(p, 1, 64);
            if (c == 0 && er < E) out[er] = p;
        }
    }
}

extern "C" void kernel_launch(void* const* d_in, const int* in_sizes, int n_in,
                              void* d_out, int out_size, void* d_ws, size_t ws_size,
                              hipStream_t stream) {
    const int*   up_e     = (const int*)d_in[0];
    const int*   ut_e     = (const int*)d_in[1];
    const int*   utag_e   = (const int*)d_in[2];
    const float* src_feat = (const float*)d_in[3];
    const float* dst_feat = (const float*)d_in[4];
    const float* up_emb   = (const float*)d_in[5];
    const float* ut_emb   = (const float*)d_in[6];
    const float* utag_emb = (const float*)d_in[7];
    const float* W_src    = (const float*)d_in[8];
    const float* b_src    = (const float*)d_in[9];
    const float* W_dst    = (const float*)d_in[10];
    const float* b_dst    = (const float*)d_in[11];
    float* out = (float*)d_out;

    const int E  = in_sizes[0] / 2;
    const int NP = in_sizes[5] / DIM;
    const int NT = in_sizes[6] / DIM;
    const int NG = in_sizes[7] / DIM;
    const int NTOT = NP + NT + NG;
    const int NB = (NTOT + 255) / 256;          // scan blocks

    // ---- workspace layout ----
    char* w = (char*)d_ws;
    int*  hist = (int*)w;                       w += (size_t)CHK * NTOT * 4;  // chunk hists
    int*  csum = (int*)w;                       w += (size_t)CHK * NTOT * 4;  // chunk prefixes
    int*  deg  = (int*)w;                       w += (size_t)NTOT * 4;
    int*  offs = (int*)w;                       w += (size_t)(NTOT + 1) * 4;
    int*  bsum = (int*)w;                       w += (size_t)1024 * 4;
    float* dinv = (float*)w;                    w += (size_t)NTOT * 4;
    w = (char*)(((uintptr_t)w + 127) & ~(uintptr_t)127);
    s16x4* wfrag = (s16x4*)w;                   w += (size_t)512 * 8;         // bf16 W frags
    w = (char*)(((uintptr_t)w + 127) & ~(uintptr_t)127);
    int*  ei   = (int*)w;                       w += (size_t)3 * E * 4;
    w = (char*)(((uintptr_t)w + 127) & ~(uintptr_t)127);
    ushort4* embh = (ushort4*)w;                w += (size_t)NTOT * 16 * 8;   // bf16 emb
    ushort4* x1h  = (ushort4*)w;                w += (size_t)NTOT * 16 * 8;   // bf16 x1
    ushort4* outh = (ushort4*)w;                // bf16 aggregated node table

    const int BT = 256;
    const int HB = 3 * RNG * CHK;               // histogram blocks (384)

    // deg histograms (atomic-free) + emb bf16 convert + W-frag build, fused
    {
        int convBlocks = (NTOT * 16 + 1023) / 1024;
        deg_cvt_kernel<<<dim3(HB + convBlocks + 1), dim3(1024), 0, stream>>>(
            up_e, ut_e, utag_e, hist,
            (const float4*)up_emb, (const float4*)ut_emb, (const float4*)utag_emb,
            embh, W_src, W_dst, wfrag, NP, NT, NG, NTOT, E);
    }

    // chunk prefixes + total degree
    sumdeg_kernel<<<dim3(NB), dim3(BT), 0, stream>>>(hist, csum, deg, NTOT);

    // global parallel exclusive scan over deg (+ dinv)
    block_sums<<<dim3(NB), dim3(BT), 0, stream>>>(deg, bsum, NTOT);
    scan_bsums<<<dim3(1), dim3(1024), 0, stream>>>(bsum, NB);
    scatter_offs<<<dim3(NB), dim3(BT), 0, stream>>>(deg, bsum, offs, dinv, NTOT, 3 * E);

    // CSR build: LDS cursors from offs+csum, XCD-aligned chunk blocks
    permute3_kernel<<<dim3(CHK * 24), dim3(1024), 0, stream>>>(
        up_e, ut_e, utag_e, offs, csum, ei, NP, NT, NG, NTOT, E);

    // conv layers over ALL nodes
    int nb = ((size_t)NTOT * 16 + BT - 1) / BT;
    conv_csr1<<<dim3(nb), dim3(BT), 0, stream>>>(offs, ei, dinv, embh, x1h, NTOT);
    conv_csr2<<<dim3(nb), dim3(BT), 0, stream>>>(offs, ei, dinv, embh, x1h, outh, NTOT);

    // final v8: 64 edges per wave (4 pipelined tiles), MFMA feature GEMM
    {
        int blocks = (E + 4 * EPT - 1) / (4 * EPT);
        final_kernel<<<dim3(blocks), dim3(BT), 0, stream>>>(
            up_e, ut_e, utag_e, src_feat, dst_feat, outh, wfrag,
            (const float4*)b_src, (const float4*)b_dst, out, E, NP, NT);
    }
}

// Round 14
// 329.065 us; speedup vs baseline: 1.0637x; 1.0637x over previous
//
#include <hip/hip_runtime.h>

#define DIM 64
#define RNG 8        // node ranges per graph (LDS-owned)
#define CHK 16       // edge chunks per graph (384 blocks ~1.5/CU)
#define LDSH 14336   // LDS histogram/cursor capacity (ints); ceil(110000/8)=13750 fits

typedef __attribute__((ext_vector_type(4))) short s16x4;
typedef __attribute__((ext_vector_type(4))) float f32x4v;

__device__ __forceinline__ float bf2f(unsigned short u) {
    union { unsigned int i; float f; } v; v.i = ((unsigned int)u) << 16; return v.f;
}
__device__ __forceinline__ unsigned short f2bf(float f) {
    union { float f; unsigned int i; } v; v.f = f;
    unsigned int r = v.i + 0x7fff + ((v.i >> 16) & 1);   // RNE (no NaN inputs here)
    return (unsigned short)(r >> 16);
}
__device__ __forceinline__ float4 u2f4(ushort4 u) {
    float4 f; f.x = bf2f(u.x); f.y = bf2f(u.y); f.z = bf2f(u.z); f.w = bf2f(u.w);
    return f;
}
__device__ __forceinline__ ushort4 f2u4(float4 f) {
    ushort4 u; u.x = f2bf(f.x); u.y = f2bf(f.y); u.z = f2bf(f.z); u.w = f2bf(f.w);
    return u;
}
__device__ __forceinline__ float4 fma4(float4 a, float s, float4 c) {
    c.x = fmaf(a.x, s, c.x); c.y = fmaf(a.y, s, c.y);
    c.z = fmaf(a.z, s, c.z); c.w = fmaf(a.w, s, c.w);
    return c;
}
__device__ __forceinline__ float4 add4(float4 a, float4 b) {
    float4 r; r.x = a.x + b.x; r.y = a.y + b.y; r.z = a.z + b.z; r.w = a.w + b.w;
    return r;
}

// ---- deg (LDS histograms, ZERO global atomics) + emb fp32->bf16 convert
//      + one ride-along block building the bf16 MFMA B-fragment table ----
__global__ __launch_bounds__(1024) void deg_cvt_kernel(
        const int* __restrict__ up, const int* __restrict__ ut,
        const int* __restrict__ ug, int* __restrict__ hist,
        const float4* __restrict__ e0, const float4* __restrict__ e1,
        const float4* __restrict__ e2, ushort4* __restrict__ embh,
        const float* __restrict__ W_s, const float* __restrict__ W_d,
        s16x4* __restrict__ wfrag,
        int NP, int NT, int NG, int NTOT, int E) {
    __shared__ int lh[LDSH];
    int b = blockIdx.x;
    const int HB = 3 * RNG * CHK;
    if (b < HB) {
        int c  = b & (CHK - 1);
        int gr = b >> 4;             // CHK==16
        int g  = gr >> 3;            // RNG==8
        int r  = gr & (RNG - 1);
        const int* edge = (g == 0) ? up : (g == 1) ? ut : ug;
        int nb = (g == 0) ? 0 : (g == 1) ? NP : NP + NT;
        int Ng = (g == 0) ? NP : (g == 1) ? NT : NG;
        int Q  = (Ng + RNG - 1) / RNG;
        int lo = r * Q;
        int hi = lo + Q; if (hi > Ng) hi = Ng;
        int nloc = hi - lo;
        for (int t = threadIdx.x; t < nloc; t += 1024) lh[t] = 0;
        __syncthreads();
        int CE = (E + CHK - 1) / CHK;
        int jb = c * CE, je = jb + CE; if (je > E) je = E;
        for (int j = jb + threadIdx.x; j < je; j += 1024) {
            int t = edge[E + j];                         // dst (local id)
            if (t >= lo && t < hi) atomicAdd(&lh[t - lo], 1);
        }
        __syncthreads();
        for (int t = threadIdx.x; t < nloc; t += 1024)
            hist[(size_t)c * NTOT + nb + lo + t] = lh[t];
        return;
    }
    int convBlocks = (NTOT * 16 + 1023) / 1024;
    if (b >= HB + convBlocks) {
        // ---- build wfrag (512 entries of s16x4) ----
        int i = threadIdx.x;
        if (i < 512) {
            int m = i >> 8;              // matrix (0=src,1=dst)
            int t = (i >> 6) & 3;        // tile
            int l = i & 63;              // lane
            int q = l >> 4, cc = l & 15;
            const float* Wm = m ? W_d : W_s;
            s16x4 v;
#pragma unroll
            for (int j = 0; j < 4; ++j)
                v[j] = (short)f2bf(Wm[(4 * q + j) * 64 + 4 * cc + t]);
            wfrag[i] = v;
        }
        return;
    }
    // ---- emb conversion blocks ----
    int i2 = (b - HB) * 1024 + threadIdx.x;
    int np16 = NP * 16, nt16 = NT * 16, ng16 = NG * 16;
    if (i2 >= np16 + nt16 + ng16) return;
    const float4* s; int j;
    if (i2 < np16)              { s = e0; j = i2; }
    else if (i2 < np16 + nt16)  { s = e1; j = i2 - np16; }
    else                        { s = e2; j = i2 - np16 - nt16; }
    embh[i2] = f2u4(s[j]);
}

// ---- chunk-prefix + total degree + per-block sums (merged: r13) ----
// deg stays in a register (run); reduce it in-block and write bsum directly,
// saving one kernel launch + one full deg re-read.
__global__ void sumdeg_kernel(const int* __restrict__ hist, int* __restrict__ csum,
                              int* __restrict__ deg, int* __restrict__ bsum, int n) {
    int i = blockIdx.x * 256 + threadIdx.x;
    int run = 0;
    if (i < n) {
#pragma unroll
        for (int c = 0; c < CHK; ++c) {
            csum[(size_t)c * n + i] = run;      // exclusive chunk prefix
            run += hist[(size_t)c * n + i];
        }
        deg[i] = run;
    }
    int v = (i < n) ? run : 0;
#pragma unroll
    for (int s = 1; s < 64; s <<= 1) v += __shfl_xor(v, s, 64);
    __shared__ int ws[4];
    if ((threadIdx.x & 63) == 0) ws[threadIdx.x >> 6] = v;
    __syncthreads();
    if (threadIdx.x == 0) bsum[blockIdx.x] = ws[0] + ws[1] + ws[2] + ws[3];
}

// ---- stage 2: exclusive scan of block sums (single block, nb <= 1024) ----
__global__ void scan_bsums(int* __restrict__ bsum, int nb) {
    int lane = threadIdx.x & 63, wid = threadIdx.x >> 6;
    int v = (threadIdx.x < nb) ? bsum[threadIdx.x] : 0;
    int x = v;
#pragma unroll
    for (int s = 1; s < 64; s <<= 1) {
        int y = __shfl_up(x, s, 64);
        if (lane >= s) x += y;
    }
    __shared__ int ws[16];
    if (lane == 63) ws[wid] = x;
    __syncthreads();
    int pre = 0;
    for (int w2 = 0; w2 < wid; ++w2) pre += ws[w2];
    if (threadIdx.x < nb) bsum[threadIdx.x] = pre + x - v;   // exclusive
}

// ---- stage 3: global exclusive offsets + dinv ----
__global__ void scatter_offs(const int* __restrict__ deg, const int* __restrict__ bpre,
                             int* __restrict__ offs, float* __restrict__ dinv,
                             int n, int total) {
    int i = blockIdx.x * 256 + threadIdx.x;
    int lane = threadIdx.x & 63, wid = threadIdx.x >> 6;
    int v = (i < n) ? deg[i] : 0;
    int x = v;
#pragma unroll
    for (int s = 1; s < 64; s <<= 1) {
        int y = __shfl_up(x, s, 64);
        if (lane >= s) x += y;
    }
    __shared__ int ws[4];
    if (lane == 63) ws[wid] = x;
    __syncthreads();
    int pre = bpre[blockIdx.x];
    for (int w2 = 0; w2 < wid; ++w2) pre += ws[w2];
    if (i < n) {
        int e = pre + x - v;
        offs[i] = e;
        dinv[i] = (v > 0) ? rsqrtf((float)v) : 0.0f;
    }
    if (i == 0) offs[n] = total;
}

// ---- permute into dst-sorted CSR order (ZERO global atomics) ----
// XCD-ALIGNED DECODE: b = c*24 + gr; 24%8==0 so b%8 == gr%8 -- all CHK chunks
// of one (g,r) land on the SAME XCD; each 64B ei line written back once, full.
__global__ __launch_bounds__(1024) void permute3_kernel(
        const int* __restrict__ up, const int* __restrict__ ut,
        const int* __restrict__ ug, const int* __restrict__ offs,
        const int* __restrict__ csum, int* __restrict__ ei,
        int NP, int NT, int NG, int NTOT, int E) {
    __shared__ int lcur[LDSH];
    int b = blockIdx.x;
    int c  = b / 24;                 // chunk (0..CHK-1); 24 = 3*RNG (g,r) pairs
    int gr = b - c * 24;             // (g,r); b%8 == gr%8 -> XCD-aligned
    int g  = gr >> 3;
    int r  = gr & (RNG - 1);
    const int* edge = (g == 0) ? up : (g == 1) ? ut : ug;
    int nb = (g == 0) ? 0 : (g == 1) ? NP : NP + NT;
    int Ng = (g == 0) ? NP : (g == 1) ? NT : NG;
    int Q  = (Ng + RNG - 1) / RNG;
    int lo = r * Q;
    int hi = lo + Q; if (hi > Ng) hi = Ng;
    int nloc = hi - lo;
    for (int t = threadIdx.x; t < nloc; t += 1024)
        lcur[t] = offs[nb + lo + t] + csum[(size_t)c * NTOT + nb + lo + t];
    __syncthreads();
    int CE = (E + CHK - 1) / CHK;
    int jb = c * CE, je = jb + CE; if (je > E) je = E;
    for (int j = jb + threadIdx.x; j < je; j += 1024) {
        int t = edge[E + j];                             // dst (local id)
        if (t >= lo && t < hi) {
            int p = atomicAdd(&lcur[t - lo], 1);         // LDS atomic (on-CU)
            ei[p] = edge[j] + nb;                        // global src id
        }
    }
}

// ---- conv layer 1: x1[n] = dinv[n] * sum_in emb[s]*dinv[s]  (bf16 rows) ----
// 8 loads in flight, 4 accumulators at chain depth 2.
__global__ void conv_csr1(const int* __restrict__ offs, const int* __restrict__ ei,
                          const float* __restrict__ dinv,
                          const ushort4* __restrict__ xin, ushort4* __restrict__ xout, int N) {
    int gid = blockIdx.x * blockDim.x + threadIdx.x;
    int n = gid >> 4, l = gid & 15;
    if (n >= N) return;
    int beg = offs[n], end = offs[n + 1];
    float4 a0 = {0.f, 0.f, 0.f, 0.f}, a1 = a0, a2 = a0, a3 = a0;
    int k = beg;
    for (; k + 7 < end; k += 8) {
        int s0 = ei[k], s1 = ei[k + 1], s2 = ei[k + 2], s3 = ei[k + 3];
        int s4 = ei[k + 4], s5 = ei[k + 5], s6 = ei[k + 6], s7 = ei[k + 7];
        float w0 = dinv[s0], w1 = dinv[s1], w2 = dinv[s2], w3 = dinv[s3];
        float w4 = dinv[s4], w5 = dinv[s5], w6 = dinv[s6], w7 = dinv[s7];
        ushort4 u0 = xin[(size_t)s0 * 16 + l];
        ushort4 u1 = xin[(size_t)s1 * 16 + l];
        ushort4 u2 = xin[(size_t)s2 * 16 + l];
        ushort4 u3 = xin[(size_t)s3 * 16 + l];
        ushort4 u4 = xin[(size_t)s4 * 16 + l];
        ushort4 u5 = xin[(size_t)s5 * 16 + l];
        ushort4 u6 = xin[(size_t)s6 * 16 + l];
        ushort4 u7 = xin[(size_t)s7 * 16 + l];
        a0 = fma4(u2f4(u0), w0, a0);
        a1 = fma4(u2f4(u1), w1, a1);
        a2 = fma4(u2f4(u2), w2, a2);
        a3 = fma4(u2f4(u3), w3, a3);
        a0 = fma4(u2f4(u4), w4, a0);
        a1 = fma4(u2f4(u5), w5, a1);
        a2 = fma4(u2f4(u6), w6, a2);
        a3 = fma4(u2f4(u7), w7, a3);
    }
    for (; k + 3 < end; k += 4) {
        int s0 = ei[k], s1 = ei[k + 1], s2 = ei[k + 2], s3 = ei[k + 3];
        float w0 = dinv[s0], w1 = dinv[s1], w2 = dinv[s2], w3 = dinv[s3];
        ushort4 u0 = xin[(size_t)s0 * 16 + l];
        ushort4 u1 = xin[(size_t)s1 * 16 + l];
        ushort4 u2 = xin[(size_t)s2 * 16 + l];
        ushort4 u3 = xin[(size_t)s3 * 16 + l];
        a0 = fma4(u2f4(u0), w0, a0);
        a1 = fma4(u2f4(u1), w1, a1);
        a2 = fma4(u2f4(u2), w2, a2);
        a3 = fma4(u2f4(u3), w3, a3);
    }
    for (; k < end; ++k) {
        int s = ei[k];
        a0 = fma4(u2f4(xin[(size_t)s * 16 + l]), dinv[s], a0);
    }
    float4 acc = add4(add4(a0, a1), add4(a2, a3));
    float sc = dinv[n];
    float4 r; r.x = acc.x * sc; r.y = acc.y * sc; r.z = acc.z * sc; r.w = acc.w * sc;
    xout[(size_t)n * 16 + l] = f2u4(r);
}

// ---- conv layer 2 + epilogue (same 8-wide MLP) ----
__global__ void conv_csr2(const int* __restrict__ offs, const int* __restrict__ ei,
                          const float* __restrict__ dinv,
                          const ushort4* __restrict__ emb, const ushort4* __restrict__ x1,
                          ushort4* __restrict__ out, int N) {
    int gid = blockIdx.x * blockDim.x + threadIdx.x;
    int n = gid >> 4, l = gid & 15;
    if (n >= N) return;
    int beg = offs[n], end = offs[n + 1];
    float4 a0 = {0.f, 0.f, 0.f, 0.f}, a1 = a0, a2 = a0, a3 = a0;
    int k = beg;
    for (; k + 7 < end; k += 8) {
        int s0 = ei[k], s1 = ei[k + 1], s2 = ei[k + 2], s3 = ei[k + 3];
        int s4 = ei[k + 4], s5 = ei[k + 5], s6 = ei[k + 6], s7 = ei[k + 7];
        float w0 = dinv[s0], w1 = dinv[s1], w2 = dinv[s2], w3 = dinv[s3];
        float w4 = dinv[s4], w5 = dinv[s5], w6 = dinv[s6], w7 = dinv[s7];
        ushort4 u0 = x1[(size_t)s0 * 16 + l];
        ushort4 u1 = x1[(size_t)s1 * 16 + l];
        ushort4 u2 = x1[(size_t)s2 * 16 + l];
        ushort4 u3 = x1[(size_t)s3 * 16 + l];
        ushort4 u4 = x1[(size_t)s4 * 16 + l];
        ushort4 u5 = x1[(size_t)s5 * 16 + l];
        ushort4 u6 = x1[(size_t)s6 * 16 + l];
        ushort4 u7 = x1[(size_t)s7 * 16 + l];
        a0 = fma4(u2f4(u0), w0, a0);
        a1 = fma4(u2f4(u1), w1, a1);
        a2 = fma4(u2f4(u2), w2, a2);
        a3 = fma4(u2f4(u3), w3, a3);
        a0 = fma4(u2f4(u4), w4, a0);
        a1 = fma4(u2f4(u5), w5, a1);
        a2 = fma4(u2f4(u6), w6, a2);
        a3 = fma4(u2f4(u7), w7, a3);
    }
    for (; k + 3 < end; k += 4) {
        int s0 = ei[k], s1 = ei[k + 1], s2 = ei[k + 2], s3 = ei[k + 3];
        float w0 = dinv[s0], w1 = dinv[s1], w2 = dinv[s2], w3 = dinv[s3];
        ushort4 u0 = x1[(size_t)s0 * 16 + l];
        ushort4 u1 = x1[(size_t)s1 * 16 + l];
        ushort4 u2 = x1[(size_t)s2 * 16 + l];
        ushort4 u3 = x1[(size_t)s3 * 16 + l];
        a0 = fma4(u2f4(u0), w0, a0);
        a1 = fma4(u2f4(u1), w1, a1);
        a2 = fma4(u2f4(u2), w2, a2);
        a3 = fma4(u2f4(u3), w3, a3);
    }
    for (; k < end; ++k) {
        int s = ei[k];
        a0 = fma4(u2f4(x1[(size_t)s * 16 + l]), dinv[s], a0);
    }
    float4 acc = add4(add4(a0, a1), add4(a2, a3));
    float sc = dinv[n];
    size_t idx = (size_t)n * 16 + l;
    float4 em = u2f4(emb[idx]), x = u2f4(x1[idx]);
    const float third = 1.0f / 3.0f;
    float4 o;
    o.x = (em.x + x.x + acc.x * sc) * third;
    o.y = (em.y + x.y + acc.y * sc) * third;
    o.z = (em.z + x.z + acc.z * sc) * third;
    o.w = (em.w + x.w + acc.w * sc) * third;
    out[idx] = f2u4(o);
}

// ---- final v7 (REVERTED from v8 per r12 pre-commitment): MFMA GEMM,
//      single-shot 16 edges/wave. Ledger: v8's 4-tile pipeline cost VGPR
//      60->88 (8->5 waves/SIMD) and the in-wave chain stayed serial ->
//      62->80us regression. Occupancy beats per-wave pipelining here
//      (3rd confirmation: r3 spill, r5 reg-features, r12 pipeline). ----
__global__ __launch_bounds__(256) void final_kernel(
        const int* __restrict__ up_e, const int* __restrict__ ut_e,
        const int* __restrict__ utag_e,
        const float* __restrict__ src_feat, const float* __restrict__ dst_feat,
        const ushort4* __restrict__ O, const s16x4* __restrict__ wfrag,
        const float4* __restrict__ b_s4, const float4* __restrict__ b_d4,
        float* __restrict__ out, int E, int NP, int NT) {
    int tid = threadIdx.x;
    int wv = tid >> 6;             // wave in block
    int l  = tid & 63;             // lane
    int c  = l & 15;               // col = dim quad (dims 4c..4c+3)
    int q  = l >> 4;               // quad (0..3)
    int e0w = (blockIdx.x * 4 + wv) * 16;
    if (e0w >= E) return;

    // ---- phase 0a: A fragments (features of the wave's 16 edges, bf16) ----
    int ea = e0w + c; if (ea > E - 1) ea = E - 1;
    float4 fa = *(const float4*)(src_feat + (size_t)ea * 16 + q * 4);
    float4 ga = *(const float4*)(dst_feat + (size_t)ea * 16 + q * 4);

    // ---- phase 0b: B fragments (precomputed bf16 table) + biases ----
    s16x4 Bs[4], Bd[4];
#pragma unroll
    for (int t = 0; t < 4; ++t) {
        Bs[t] = wfrag[t * 64 + l];
        Bd[t] = wfrag[256 + t * 64 + l];
    }
    float4 bsv = b_s4[c], bdv = b_d4[c];

    s16x4 As, Ad;
    As[0] = (short)f2bf(fa.x); As[1] = (short)f2bf(fa.y);
    As[2] = (short)f2bf(fa.z); As[3] = (short)f2bf(fa.w);
    Ad[0] = (short)f2bf(ga.x); Ad[1] = (short)f2bf(ga.y);
    Ad[2] = (short)f2bf(ga.z); Ad[3] = (short)f2bf(ga.w);

    // ---- phase 1: edge indices + 24 O-row gathers ----
    ushort4 as[4][3], bs[4][3];
#pragma unroll
    for (int r = 0; r < 4; ++r) {
        int e = e0w + q * 4 + r; if (e > E - 1) e = E - 1;
        int sp = up_e[e],             dp = up_e[E + e];
        int st = ut_e[e] + NP,        dt = ut_e[E + e] + NP;
        int sg = utag_e[e] + NP + NT, dg = utag_e[E + e] + NP + NT;
        as[r][0] = O[(size_t)sp * 16 + c];
        as[r][1] = O[(size_t)st * 16 + c];
        as[r][2] = O[(size_t)sg * 16 + c];
        bs[r][0] = O[(size_t)dp * 16 + c];
        bs[r][1] = O[(size_t)dt * 16 + c];
        bs[r][2] = O[(size_t)dg * 16 + c];
    }
    __builtin_amdgcn_sched_barrier(0);   // pin gathers above the MFMAs

    // ---- phase 2: 8 MFMAs (wait only on A/B loads; gathers stay in flight) ----
    f32x4v Cs[4], Cd[4];
    f32x4v zz = {0.f, 0.f, 0.f, 0.f};
#pragma unroll
    for (int t = 0; t < 4; ++t) {
        Cs[t] = __builtin_amdgcn_mfma_f32_16x16x16bf16_1k(As, Bs[t], zz, 0, 0, 0);
        Cd[t] = __builtin_amdgcn_mfma_f32_16x16x16bf16_1k(Ad, Bd[t], zz, 0, 0, 0);
    }

    // ---- phase 3: epilogue (waits on gathers); C/D: row=(q*4+r), col=c ----
    const float third = 1.0f / 3.0f;
#pragma unroll
    for (int r = 0; r < 4; ++r) {
        int er = e0w + q * 4 + r;
        float4 fsv, fdv;
        fsv.x = Cs[0][r] + bsv.x; fsv.y = Cs[1][r] + bsv.y;
        fsv.z = Cs[2][r] + bsv.z; fsv.w = Cs[3][r] + bsv.w;
        fdv.x = Cd[0][r] + bdv.x; fdv.y = Cd[1][r] + bdv.y;
        fdv.z = Cd[2][r] + bdv.z; fdv.w = Cd[3][r] + bdv.w;
        float4 vp = u2f4(as[r][0]), vt = u2f4(as[r][1]), vg = u2f4(as[r][2]);
        float4 P, Q;
        P.x = (vp.x + vt.x + vg.x) * third + fsv.x;
        P.y = (vp.y + vt.y + vg.y) * third + fsv.y;
        P.z = (vp.z + vt.z + vg.z) * third + fsv.z;
        P.w = (vp.w + vt.w + vg.w) * third + fsv.w;
        vp = u2f4(bs[r][0]); vt = u2f4(bs[r][1]); vg = u2f4(bs[r][2]);
        Q.x = (vp.x + vt.x + vg.x) * third + fdv.x;
        Q.y = (vp.y + vt.y + vg.y) * third + fdv.y;
        Q.z = (vp.z + vt.z + vg.z) * third + fdv.z;
        Q.w = (vp.w + vt.w + vg.w) * third + fdv.w;
        float p = P.x * Q.x + P.y * Q.y + P.z * Q.z + P.w * Q.w;
        p += __shfl_xor(p, 8, 64);
        p += __shfl_xor(p, 4, 64);
        p += __shfl_xor(p, 2, 64);
        p += __shfl_xor(p, 1, 64);
        if (c == 0 && er < E) out[er] = p;
    }
}

extern "C" void kernel_launch(void* const* d_in, const int* in_sizes, int n_in,
                              void* d_out, int out_size, void* d_ws, size_t ws_size,
                              hipStream_t stream) {
    const int*   up_e     = (const int*)d_in[0];
    const int*   ut_e     = (const int*)d_in[1];
    const int*   utag_e   = (const int*)d_in[2];
    const float* src_feat = (const float*)d_in[3];
    const float* dst_feat = (const float*)d_in[4];
    const float* up_emb   = (const float*)d_in[5];
    const float* ut_emb   = (const float*)d_in[6];
    const float* utag_emb = (const float*)d_in[7];
    const float* W_src    = (const float*)d_in[8];
    const float* b_src    = (const float*)d_in[9];
    const float* W_dst    = (const float*)d_in[10];
    const float* b_dst    = (const float*)d_in[11];
    float* out = (float*)d_out;

    const int E  = in_sizes[0] / 2;
    const int NP = in_sizes[5] / DIM;
    const int NT = in_sizes[6] / DIM;
    const int NG = in_sizes[7] / DIM;
    const int NTOT = NP + NT + NG;
    const int NB = (NTOT + 255) / 256;          // scan blocks

    // ---- workspace layout ----
    char* w = (char*)d_ws;
    int*  hist = (int*)w;                       w += (size_t)CHK * NTOT * 4;  // chunk hists
    int*  csum = (int*)w;                       w += (size_t)CHK * NTOT * 4;  // chunk prefixes
    int*  deg  = (int*)w;                       w += (size_t)NTOT * 4;
    int*  offs = (int*)w;                       w += (size_t)(NTOT + 1) * 4;
    int*  bsum = (int*)w;                       w += (size_t)1024 * 4;
    float* dinv = (float*)w;                    w += (size_t)NTOT * 4;
    w = (char*)(((uintptr_t)w + 127) & ~(uintptr_t)127);
    s16x4* wfrag = (s16x4*)w;                   w += (size_t)512 * 8;         // bf16 W frags
    w = (char*)(((uintptr_t)w + 127) & ~(uintptr_t)127);
    int*  ei   = (int*)w;                       w += (size_t)3 * E * 4;
    w = (char*)(((uintptr_t)w + 127) & ~(uintptr_t)127);
    ushort4* embh = (ushort4*)w;                w += (size_t)NTOT * 16 * 8;   // bf16 emb
    ushort4* x1h  = (ushort4*)w;                w += (size_t)NTOT * 16 * 8;   // bf16 x1
    ushort4* outh = (ushort4*)w;                // bf16 aggregated node table

    const int BT = 256;
    const int HB = 3 * RNG * CHK;               // histogram blocks (384)

    // deg histograms (atomic-free) + emb bf16 convert + W-frag build, fused
    {
        int convBlocks = (NTOT * 16 + 1023) / 1024;
        deg_cvt_kernel<<<dim3(HB + convBlocks + 1), dim3(1024), 0, stream>>>(
            up_e, ut_e, utag_e, hist,
            (const float4*)up_emb, (const float4*)ut_emb, (const float4*)utag_emb,
            embh, W_src, W_dst, wfrag, NP, NT, NG, NTOT, E);
    }

    // chunk prefixes + total degree + block sums (merged)
    sumdeg_kernel<<<dim3(NB), dim3(BT), 0, stream>>>(hist, csum, deg, bsum, NTOT);

    // exclusive scan of block sums, then offsets + dinv
    scan_bsums<<<dim3(1), dim3(1024), 0, stream>>>(bsum, NB);
    scatter_offs<<<dim3(NB), dim3(BT), 0, stream>>>(deg, bsum, offs, dinv, NTOT, 3 * E);

    // CSR build: LDS cursors from offs+csum, XCD-aligned chunk blocks
    permute3_kernel<<<dim3(CHK * 24), dim3(1024), 0, stream>>>(
        up_e, ut_e, utag_e, offs, csum, ei, NP, NT, NG, NTOT, E);

    // conv layers over ALL nodes
    int nb = ((size_t)NTOT * 16 + BT - 1) / BT;
    conv_csr1<<<dim3(nb), dim3(BT), 0, stream>>>(offs, ei, dinv, embh, x1h, NTOT);
    conv_csr2<<<dim3(nb), dim3(BT), 0, stream>>>(offs, ei, dinv, embh, x1h, outh, NTOT);

    // final v7: 16 edges per wave, MFMA feature GEMM
    {
        int blocks = (E + 63) / 64;
        final_kernel<<<dim3(blocks), dim3(BT), 0, stream>>>(
            up_e, ut_e, utag_e, src_feat, dst_feat, outh, wfrag,
            (const float4*)b_src, (const float4*)b_dst, out, E, NP, NT);
    }
}